// Round 5
// baseline (74.508 us; speedup 1.0000x reference)
//
#include <hip/hip_runtime.h>
#include <hip/hip_bf16.h>

// Problem constants (S4Layer: T=4096, B=16, D=128, S=256)
#define T_  4096
#define B_  16
#define D_  128
#define S_  256
#define WND 64             // scan chunk length
#define C4  (T_/WND)       // 64 chunks
#define NTI (T_/4)         // 1024 GEMM tiles (4t x 16b = 64 rows each)

using bf8   = __attribute__((ext_vector_type(8))) short;   // 8 bf16 (4 VGPRs)
using f32x4 = __attribute__((ext_vector_type(4))) float;   // MFMA acc

__device__ inline float bfbits(unsigned short h) {
    return __builtin_bit_cast(float, (unsigned)h << 16);
}

// ---------------- K1: parameters -------------------------------------------
__global__ __launch_bounds__(256) void k_params(
        const float* __restrict__ lna, const float* __restrict__ bmat,
        const float* __restrict__ ldt,
        float* __restrict__ abar, float* __restrict__ a64,
        __hip_bfloat16* __restrict__ bbar) {
    if (blockIdx.x < 128) {
        int idx = blockIdx.x * 256 + threadIdx.x;   // (s,d)
        int s = idx >> 7;
        float la = fminf(fmaxf(lna[s], -8.f), 4.f);
        float ar = -expf(la);
        float lt = fminf(fmaxf(ldt[s], -8.f), 1.f);
        float dt = expf(lt);
        float xx = dt * ar;
        float ratio = (fabsf(xx) < 1e-6f) ? dt : (expm1f(xx) / ar);
        bbar[idx] = __float2bfloat16(ratio * bmat[idx]);
    } else {
        int s = threadIdx.x;
        float la = fminf(fmaxf(lna[s], -8.f), 4.f);
        float ar = -expf(la);
        float lt = fminf(fmaxf(ldt[s], -8.f), 1.f);
        float dt = expf(lt);
        float ab = expf(dt * ar);
        abar[s] = ab;
        float p = ab;
#pragma unroll
        for (int j = 0; j < 6; ++j) p *= p;     // a^64 by squaring
        a64[s] = p;
    }
}

// ---------------- K2: GEMM -> ub[t][b][s] (bf16), fully coalesced ----------
// Tile = 64 CONTIGUOUS rows of A (= 4 t x 16 b): dense 32 KiB stage-in and
// dense 32 KiB store-out (LDS-transposed). 1024 blocks, 4 waves each.
__global__ __launch_bounds__(256, 4) void k_gemm(
        const float* __restrict__ x, const __hip_bfloat16* __restrict__ bbar,
        __hip_bfloat16* __restrict__ ub) {
    const int tile = blockIdx.x;
    __shared__ char LDS[64 * 512];     // 32 KiB: stage-A in [0,16K), then P
    const int tid = threadIdx.x, lane = tid & 63, w = tid >> 6;
    const int l15 = lane & 15, l4 = lane >> 4;

    // Stage A: 64 rows x 128 d, fp32 -> bf16, XOR swizzle ^((row&7)<<4)
    const float* xt = x + (size_t)tile * 64 * D_;
#pragma unroll
    for (int k = 0; k < 8; ++k) {
        int idx = tid + k * 256;                 // float4 index in tile
        int row = idx >> 5, seg = idx & 31;
        float4 v = *(const float4*)(xt + idx * 4);
        __hip_bfloat162 lo = __float22bfloat162_rn(make_float2(v.x, v.y));
        __hip_bfloat162 hi = __float22bfloat162_rn(make_float2(v.z, v.w));
        uint2 pk = { *(unsigned*)&lo, *(unsigned*)&hi };
        int off = (row * 256 + seg * 8) ^ ((row & 7) << 4);
        *(uint2*)(LDS + off) = pk;
    }
    __syncthreads();

    // MFMA: wave w owns s in [w*64,(w+1)*64); acc[i][j]: row=i*16+l4*4+r
    f32x4 acc[4][4] = {};
    for (int j = 0; j < 4; ++j) {
        bf8 bfrag[4];
        int s = w * 64 + j * 16 + l15;
#pragma unroll
        for (int kk = 0; kk < 4; ++kk)
            bfrag[kk] = *(const bf8*)((const short*)bbar + s * D_ + kk * 32 + l4 * 8);
#pragma unroll
        for (int i = 0; i < 4; ++i) {
            bf8 af[4];
            int tr = i * 16 + l15;
#pragma unroll
            for (int kk = 0; kk < 4; ++kk) {
                int off = (tr * 256 + kk * 64 + l4 * 16) ^ ((tr & 7) << 4);
                af[kk] = *(const bf8*)(LDS + off);
            }
#pragma unroll
            for (int kk = 0; kk < 4; ++kk)
                acc[i][j] = __builtin_amdgcn_mfma_f32_16x16x32_bf16(
                                af[kk], bfrag[kk], acc[i][j], 0, 0, 0);
        }
    }
    __syncthreads();   // done reading staged A; LDS now becomes P[row][s]

    // P -> LDS bf16: addr = row*512 + s*2, XOR l4<<5 ((row>>2)&3 == l4 here)
#pragma unroll
    for (int i = 0; i < 4; ++i)
#pragma unroll
        for (int j = 0; j < 4; ++j) {
            int s = w * 64 + j * 16 + l15;
#pragma unroll
            for (int r = 0; r < 4; ++r) {
                int row = i * 16 + l4 * 4 + r;
                int off = (row * 512 + s * 2) ^ (l4 << 5);
                *(unsigned short*)(LDS + off) =
                    __hip_bfloat16_raw(__float2bfloat16(acc[i][j][r])).x;
            }
        }
    __syncthreads();

    // Flat copy: 32 KiB, 1 KiB per wave-instr, swizzle uniform per (k,wave)
    char* op = (char*)ub + (size_t)tile * 32768;
#pragma unroll
    for (int k = 0; k < 8; ++k) {
        int o = k * 4096 + tid * 16;
        int swz = (2 * k + (w >> 1)) & 3;
        uint4 v = *(uint4*)(LDS + (o ^ (swz << 5)));
        *(uint4*)(op + o) = v;
    }
}

// ---------------- K3: chunk end-states from ub -----------------------------
// e64[c,b,s] = Horner_{t=0..63}( a ) over ub[c*64+t][b][s]
__global__ __launch_bounds__(256) void k_e64(
        const __hip_bfloat16* __restrict__ ub, const float* __restrict__ abar,
        float* __restrict__ e64) {
    const int c = blockIdx.x, b = blockIdx.y, s = threadIdx.x;
    const float a = abar[s];
    const __hip_bfloat16* up = ub + ((size_t)(c * WND) * B_ + b) * S_ + s;
    float e = 0.f;
#pragma unroll 8
    for (int t = 0; t < WND; ++t) {
        e = fmaf(a, e, __bfloat162float(*up));
        up += (size_t)B_ * S_;
    }
    e64[((size_t)c * B_ + b) * S_ + s] = e;
}

// ---------------- K4: redundant carry + scan + out -------------------------
__global__ __launch_bounds__(256) void k_scan(
        const __hip_bfloat16* __restrict__ ub, const float* __restrict__ e64,
        const float* __restrict__ abar, const float* __restrict__ a64,
        const float* __restrict__ z0, float* __restrict__ out) {
    const int c = blockIdx.x, b = blockIdx.y, s = threadIdx.x;
    const float a = abar[s];
    // carry-in over previous chunks (e64 is 1 MiB, L2-hot broadcast)
    float z = z0[b * S_ + s];
    {
        const float aw = a64[s];
        const float* ep = e64 + b * S_ + s;
        for (int cp = 0; cp < c; ++cp)
            z = fmaf(aw, z, ep[(size_t)cp * B_ * S_]);
    }
    const __hip_bfloat16* up = ub + ((size_t)(c * WND) * B_ + b) * S_ + s;
    float* op = out + ((size_t)(c * WND) * B_ + b) * S_ + s;
#pragma unroll 16
    for (int t = 0; t < WND; ++t) {
        z = fmaf(a, z, __bfloat162float(*up));
        *op = z;
        up += (size_t)B_ * S_;
        op += (size_t)B_ * S_;
    }
}

extern "C" void kernel_launch(void* const* d_in, const int* in_sizes, int n_in,
                              void* d_out, int out_size, void* d_ws, size_t ws_size,
                              hipStream_t stream) {
    const float* x   = (const float*)d_in[0];  // [T,B,D]
    const float* z0  = (const float*)d_in[1];  // [B,S]
    const float* lna = (const float*)d_in[2];  // [S]
    const float* bm  = (const float*)d_in[3];  // [S,D]
    const float* ldt = (const float*)d_in[4];  // [S]
    float* out = (float*)d_out;

    char* ws = (char*)d_ws;
    float*          abar = (float*)ws;                              // 1 KiB
    float*          a64  = (float*)(ws + 4096);                     // 1 KiB
    __hip_bfloat16* bbar = (__hip_bfloat16*)(ws + 8192);            // 64 KiB
    float*          e64  = (float*)(ws + (128 << 10));              // 1 MiB
    __hip_bfloat16* ub   = (__hip_bfloat16*)(ws + (4 << 20));       // 32 MiB [t][b][s]

    k_params<<<129, 256, 0, stream>>>(lna, bm, ldt, abar, a64, bbar);
    k_gemm<<<NTI, 256, 0, stream>>>(x, bbar, ub);
    k_e64<<<dim3(C4, B_), 256, 0, stream>>>(ub, abar, e64);
    k_scan<<<dim3(C4, B_), 256, 0, stream>>>(ub, e64, abar, a64, z0, out);
}

// Round 7
// 58.673 us; speedup vs baseline: 1.2699x; 1.2699x over previous
//
#include <hip/hip_runtime.h>
#include <hip/hip_bf16.h>

// Problem constants (S4Layer: T=4096, B=16, D=128, S=256)
#define T_  4096
#define B_  16
#define D_  128
#define S_  256
#define WND 64             // scan chunk length
#define C4  (T_/WND)       // 64 chunks
#define NTI (T_/4)         // 1024 GEMM tiles (4t x 16b = 64 contiguous rows each)

using bf8   = __attribute__((ext_vector_type(8))) short;   // 8 bf16 (4 VGPRs)
using f32x4 = __attribute__((ext_vector_type(4))) float;   // MFMA acc

__device__ inline float bfbits(unsigned short h) {
    return __builtin_bit_cast(float, (unsigned)h << 16);
}

// ---------------- K1: parameters -------------------------------------------
__global__ __launch_bounds__(256) void k_params(
        const float* __restrict__ lna, const float* __restrict__ bmat,
        const float* __restrict__ ldt,
        float* __restrict__ abar, float* __restrict__ a64,
        __hip_bfloat16* __restrict__ bbar) {
    if (blockIdx.x < 128) {
        int idx = blockIdx.x * 256 + threadIdx.x;   // (s,d)
        int s = idx >> 7;
        float la = fminf(fmaxf(lna[s], -8.f), 4.f);
        float ar = -expf(la);
        float lt = fminf(fmaxf(ldt[s], -8.f), 1.f);
        float dt = expf(lt);
        float xx = dt * ar;
        float ratio = (fabsf(xx) < 1e-6f) ? dt : (expm1f(xx) / ar);
        bbar[idx] = __float2bfloat16(ratio * bmat[idx]);
    } else {
        int s = threadIdx.x;
        float la = fminf(fmaxf(lna[s], -8.f), 4.f);
        float ar = -expf(la);
        float lt = fminf(fmaxf(ldt[s], -8.f), 1.f);
        float dt = expf(lt);
        float ab = expf(dt * ar);
        abar[s] = ab;
        float p = ab;
#pragma unroll
        for (int j = 0; j < 6; ++j) p *= p;     // a^64 by squaring
        a64[s] = p;
    }
}

// ---------------- K2: GEMM -> ub[b][t][s] (bf16) ---------------------------
// Tile = 64 CONTIGUOUS (t,b) rows of x (= 4 t x 16 b): dense 32 KiB stage-in;
// LDS-transposed epilogue emits 16 chunks of 2 KiB contiguous [b][t][s] data
// (1 KiB per wave-instruction). 1024 blocks, 4 waves each, 4 blocks/CU.
__global__ __launch_bounds__(256, 4) void k_gemm(
        const float* __restrict__ x, const __hip_bfloat16* __restrict__ bbar,
        __hip_bfloat16* __restrict__ ub) {
    const int tile = blockIdx.x;
    __shared__ char LDS[64 * 512];     // 32 KiB: stage-A in [0,16K), then P
    const int tid = threadIdx.x, lane = tid & 63, w = tid >> 6;
    const int l15 = lane & 15, l4 = lane >> 4;

    // Stage A: 64 rows x 128 d, fp32 -> bf16, XOR swizzle ^((row&7)<<4)
    const float* xt = x + (size_t)tile * 64 * D_;
#pragma unroll
    for (int k = 0; k < 8; ++k) {
        int idx = tid + k * 256;                 // float4 index in tile
        int row = idx >> 5, seg = idx & 31;
        float4 v = *(const float4*)(xt + idx * 4);
        __hip_bfloat162 lo = __float22bfloat162_rn(make_float2(v.x, v.y));
        __hip_bfloat162 hi = __float22bfloat162_rn(make_float2(v.z, v.w));
        uint2 pk = { *(unsigned*)&lo, *(unsigned*)&hi };
        int off = (row * 256 + seg * 8) ^ ((row & 7) << 4);
        *(uint2*)(LDS + off) = pk;
    }
    __syncthreads();

    // MFMA: wave w owns s in [w*64,(w+1)*64); acc row = i*16 + l4*4 + r
    f32x4 acc[4][4] = {};
    for (int j = 0; j < 4; ++j) {
        bf8 bfrag[4];
        int s = w * 64 + j * 16 + l15;
#pragma unroll
        for (int kk = 0; kk < 4; ++kk)
            bfrag[kk] = *(const bf8*)((const short*)bbar + s * D_ + kk * 32 + l4 * 8);
#pragma unroll
        for (int i = 0; i < 4; ++i) {
            bf8 af[4];
            int tr = i * 16 + l15;
#pragma unroll
            for (int kk = 0; kk < 4; ++kk) {
                int off = (tr * 256 + kk * 64 + l4 * 16) ^ ((tr & 7) << 4);
                af[kk] = *(const bf8*)(LDS + off);
            }
#pragma unroll
            for (int kk = 0; kk < 4; ++kk)
                acc[i][j] = __builtin_amdgcn_mfma_f32_16x16x32_bf16(
                                af[kk], bfrag[kk], acc[i][j], 0, 0, 0);
        }
    }
    __syncthreads();   // A reads done; LDS becomes P[row][s] (row = t_l*16+b_l)

    // P -> LDS bf16: addr = row*512 + s*2, XOR key ((row>>2)&3) == l4 here
#pragma unroll
    for (int i = 0; i < 4; ++i)
#pragma unroll
        for (int j = 0; j < 4; ++j) {
            int s = w * 64 + j * 16 + l15;
#pragma unroll
            for (int r = 0; r < 4; ++r) {
                int row = i * 16 + l4 * 4 + r;
                int off = (row * 512 + s * 2) ^ (l4 << 5);
                *(unsigned short*)(LDS + off) =
                    __hip_bfloat16_raw(__float2bfloat16(acc[i][j][r])).x;
            }
        }
    __syncthreads();

    // Copy out to [b][t][s]: per b_local a 2 KiB contiguous chunk (4 t x 256 s).
    // 32 instructions = 4 waves x 8; each is 1 KiB contiguous global store.
#pragma unroll
    for (int h = 0; h < 8; ++h) {
        int b = w * 4 + (h >> 1), half = h & 1;
        int o = half * 1024 + lane * 16;          // byte offset within chunk
        int t_local = o >> 9;                     // 512 B per t row
        int sb = (lane & 31) * 16;                // byte offset within row
        int row = t_local * 16 + b;               // LDS P row index
        int laddr = (row * 512 + sb) ^ (((b >> 2) & 3) << 5);
        uint4 v = *(uint4*)(LDS + laddr);
        char* gp = (char*)(ub + ((size_t)b * T_ + tile * 4) * S_) + o;
        *(uint4*)gp = v;
    }
}

// ---------------- K3: chunk end-states (contiguous window) -----------------
// e64[c,b,s] = Horner_a over ub[b][c*64+t][s], weight a^(63-t)
__global__ __launch_bounds__(256) void k_e64(
        const __hip_bfloat16* __restrict__ ub, const float* __restrict__ abar,
        float* __restrict__ e64) {
    const int c = blockIdx.x, b = blockIdx.y, s = threadIdx.x;
    const float a = abar[s];
    const __hip_bfloat16* up = ub + ((size_t)b * T_ + c * WND) * S_ + s;
    float e = 0.f;
#pragma unroll 16
    for (int t = 0; t < WND; ++t) {
        e = fmaf(a, e, __bfloat162float(*up));
        up += S_;
    }
    e64[((size_t)c * B_ + b) * S_ + s] = e;
}

// ---------------- K4: carry scan (batch-load then serial fma) --------------
__global__ __launch_bounds__(256) void k_carry(
        const float* __restrict__ e64, const float* __restrict__ a64,
        const float* __restrict__ z0, float* __restrict__ cin) {
    const int b = blockIdx.x, s = threadIdx.x;
    float ev[C4];
#pragma unroll
    for (int c = 0; c < C4; ++c)
        ev[c] = e64[((size_t)c * B_ + b) * S_ + s];   // independent, deep ILP
    float aw = a64[s];
    float Z = z0[b * S_ + s];
#pragma unroll
    for (int c = 0; c < C4; ++c) {
        cin[((size_t)c * B_ + b) * S_ + s] = Z;
        Z = fmaf(aw, Z, ev[c]);
    }
}

// ---------------- K5: per-chunk scan + out ----------------------------------
__global__ __launch_bounds__(256) void k_scan(
        const __hip_bfloat16* __restrict__ ub, const float* __restrict__ cin,
        const float* __restrict__ abar, float* __restrict__ out) {
    const int c = blockIdx.x, b = blockIdx.y, s = threadIdx.x;
    const float a = abar[s];
    float z = cin[((size_t)c * B_ + b) * S_ + s];
    const __hip_bfloat16* up = ub + ((size_t)b * T_ + c * WND) * S_ + s;
    float* op = out + ((size_t)(c * WND) * B_ + b) * S_ + s;
#pragma unroll 16
    for (int t = 0; t < WND; ++t) {
        z = fmaf(a, z, __bfloat162float(*up));
        *op = z;
        up += S_;
        op += (size_t)B_ * S_;
    }
}

extern "C" void kernel_launch(void* const* d_in, const int* in_sizes, int n_in,
                              void* d_out, int out_size, void* d_ws, size_t ws_size,
                              hipStream_t stream) {
    const float* x   = (const float*)d_in[0];  // [T,B,D]
    const float* z0  = (const float*)d_in[1];  // [B,S]
    const float* lna = (const float*)d_in[2];  // [S]
    const float* bm  = (const float*)d_in[3];  // [S,D]
    const float* ldt = (const float*)d_in[4];  // [S]
    float* out = (float*)d_out;

    char* ws = (char*)d_ws;
    float*          abar = (float*)ws;                              // 1 KiB
    float*          a64  = (float*)(ws + 4096);                     // 1 KiB
    __hip_bfloat16* bbar = (__hip_bfloat16*)(ws + 8192);            // 64 KiB
    float*          e64  = (float*)(ws + (128 << 10));              // 1 MiB
    float*          cin  = (float*)(ws + (128 << 10) + (1 << 20));  // 1 MiB
    __hip_bfloat16* ub   = (__hip_bfloat16*)(ws + (4 << 20));       // 32 MiB [b][t][s]

    k_params<<<129, 256, 0, stream>>>(lna, bm, ldt, abar, a64, bbar);
    k_gemm<<<NTI, 256, 0, stream>>>(x, bbar, ub);
    k_e64<<<dim3(C4, B_), 256, 0, stream>>>(ub, abar, e64);
    k_carry<<<B_, 256, 0, stream>>>(e64, a64, z0, cin);
    k_scan<<<dim3(C4, B_), 256, 0, stream>>>(ub, cin, abar, out);
}

// Round 8
// 48.574 us; speedup vs baseline: 1.5339x; 1.2079x over previous
//
#include <hip/hip_runtime.h>
#include <hip/hip_bf16.h>

// Problem constants (S4Layer: T=4096, B=16, D=128, S=256)
#define T_  4096
#define B_  16
#define D_  128
#define S_  256
#define WND 64             // chunk length = GEMM t-tile
#define C4  (T_/WND)       // 64 chunks

using bf8   = __attribute__((ext_vector_type(8))) short;   // 8 bf16 (4 VGPRs)
using f32x4 = __attribute__((ext_vector_type(4))) float;   // MFMA acc

__device__ inline float bfbits(unsigned short h) {
    return __builtin_bit_cast(float, (unsigned)h << 16);
}
__device__ inline unsigned short bf16bits(float f) {
    return __hip_bfloat16_raw(__float2bfloat16(f)).x;
}

// ---------------- K1: parameters -------------------------------------------
__global__ __launch_bounds__(256) void k_params(
        const float* __restrict__ lna, const float* __restrict__ bmat,
        const float* __restrict__ ldt,
        float* __restrict__ abar, float* __restrict__ a64,
        __hip_bfloat16* __restrict__ bbar) {
    if (blockIdx.x < 128) {
        int idx = blockIdx.x * 256 + threadIdx.x;   // (s,d)
        int s = idx >> 7;
        float la = fminf(fmaxf(lna[s], -8.f), 4.f);
        float ar = -expf(la);
        float lt = fminf(fmaxf(ldt[s], -8.f), 1.f);
        float dt = expf(lt);
        float xx = dt * ar;
        float ratio = (fabsf(xx) < 1e-6f) ? dt : (expm1f(xx) / ar);
        bbar[idx] = __float2bfloat16(ratio * bmat[idx]);
    } else {
        int s = threadIdx.x;
        float la = fminf(fmaxf(lna[s], -8.f), 4.f);
        float ar = -expf(la);
        float lt = fminf(fmaxf(ldt[s], -8.f), 1.f);
        float dt = expf(lt);
        float ab = expf(dt * ar);
        abar[s] = ab;
        float p = ab;
#pragma unroll
        for (int j = 0; j < 6; ++j) p *= p;     // a^64 by squaring
        a64[s] = p;
    }
}

// ---------------- K2: GEMM + e64 -> ub[b][t][s] (bf16) ---------------------
// Block (c,b): 64t x 256s tile. e64 Horner straight from bf16-rounded acc
// (no ub re-read); LDS-transposed epilogue emits ONE contiguous 32 KiB run.
__global__ __launch_bounds__(256, 4) void k_gemm(
        const float* __restrict__ x, const __hip_bfloat16* __restrict__ bbar,
        const float* __restrict__ abar,
        __hip_bfloat16* __restrict__ ub, float* __restrict__ e64) {
    const int c = blockIdx.x, b = blockIdx.y;
    __shared__ char LDS[WND * 512];    // 32 KiB: A-stage in [0,16K), then P
    const int tid = threadIdx.x, lane = tid & 63, w = tid >> 6;
    const int l15 = lane & 15, l4 = lane >> 4;

    // Stage A: rows t'=0..63 of batch b, fp32 -> bf16, swizzle ^((row&7)<<4)
#pragma unroll
    for (int k = 0; k < 8; ++k) {
        int idx = tid + k * 256;
        int row = idx >> 5, seg = idx & 31;
        float4 v = *(const float4*)(x + ((size_t)(c * WND + row) * B_ + b) * D_ + seg * 4);
        __hip_bfloat162 lo = __float22bfloat162_rn(make_float2(v.x, v.y));
        __hip_bfloat162 hi = __float22bfloat162_rn(make_float2(v.z, v.w));
        uint2 pk = { *(unsigned*)&lo, *(unsigned*)&hi };
        int off = (row * 256 + seg * 8) ^ ((row & 7) << 4);
        *(uint2*)(LDS + off) = pk;
    }
    __syncthreads();

    // MFMA: wave w owns s in [w*64,(w+1)*64); acc row = i*16 + l4*4 + r
    f32x4 acc[4][4] = {};
    for (int j = 0; j < 4; ++j) {
        bf8 bfrag[4];
        int s = w * 64 + j * 16 + l15;
#pragma unroll
        for (int kk = 0; kk < 4; ++kk)
            bfrag[kk] = *(const bf8*)((const short*)bbar + s * D_ + kk * 32 + l4 * 8);
#pragma unroll
        for (int i = 0; i < 4; ++i) {
            bf8 af[4];
            int tr = i * 16 + l15;
#pragma unroll
            for (int kk = 0; kk < 4; ++kk) {
                int off = (tr * 256 + kk * 64 + l4 * 16) ^ ((tr & 7) << 4);
                af[kk] = *(const bf8*)(LDS + off);
            }
#pragma unroll
            for (int kk = 0; kk < 4; ++kk)
                acc[i][j] = __builtin_amdgcn_mfma_f32_16x16x32_bf16(
                                af[kk], bfrag[kk], acc[i][j], 0, 0, 0);
        }
    }
    __syncthreads();   // all A reads done; LDS becomes P[t'][s] bf16

    // e64 Horner (bf16-rounded, matches scan input) + P -> LDS (swizzled).
    // t' = i*16 + l4*4 + r ; weight a^(63-t') = a^(3-r)*a^(16(3-i))*a^(4(3-l4))
#pragma unroll
    for (int j = 0; j < 4; ++j) {
        int s = w * 64 + j * 16 + l15;
        float a  = abar[s];
        float a2 = a * a, a4 = a2 * a2, a8 = a4 * a4, a16 = a8 * a8;
        float lf = (l4 == 0) ? a8 * a4 : (l4 == 1) ? a8 : (l4 == 2) ? a4 : 1.f;
        float e = 0.f;
#pragma unroll
        for (int i = 0; i < 4; ++i) {
            unsigned short h0 = bf16bits(acc[i][j][0]);
            unsigned short h1 = bf16bits(acc[i][j][1]);
            unsigned short h2 = bf16bits(acc[i][j][2]);
            unsigned short h3 = bf16bits(acc[i][j][3]);
            float inner = bfbits(h0);
            inner = fmaf(inner, a, bfbits(h1));
            inner = fmaf(inner, a, bfbits(h2));
            inner = fmaf(inner, a, bfbits(h3));
            e = fmaf(e, a16, inner);
            int row0 = i * 16 + l4 * 4;            // ((row>>2)&3) == l4 here
            *(unsigned short*)(LDS + (((row0    ) * 512 + s * 2) ^ (l4 << 5))) = h0;
            *(unsigned short*)(LDS + (((row0 + 1) * 512 + s * 2) ^ (l4 << 5))) = h1;
            *(unsigned short*)(LDS + (((row0 + 2) * 512 + s * 2) ^ (l4 << 5))) = h2;
            *(unsigned short*)(LDS + (((row0 + 3) * 512 + s * 2) ^ (l4 << 5))) = h3;
        }
        e *= lf;
        e += __shfl_xor(e, 16);
        e += __shfl_xor(e, 32);
        if (l4 == 0) e64[((size_t)c * B_ + b) * S_ + s] = e;
    }
    __syncthreads();

    // Flat copy: ONE contiguous 32 KiB run -> ub[b][c*64 .. c*64+63][*]
    char* op = (char*)(ub + ((size_t)b * T_ + c * WND) * S_);
#pragma unroll
    for (int k = 0; k < 8; ++k) {
        int o = k * 4096 + tid * 16;
        int swz = (2 * k + (w >> 1)) & 3;          // = ((o>>11)&3)
        uint4 v = *(uint4*)(LDS + (o ^ (swz << 5)));
        *(uint4*)(op + o) = v;
    }
}

// ---------------- K3: carry scan (batch-load then serial fma) --------------
__global__ __launch_bounds__(256) void k_carry(
        const float* __restrict__ e64, const float* __restrict__ a64,
        const float* __restrict__ z0, float* __restrict__ cin) {
    const int b = blockIdx.x, s = threadIdx.x;
    float ev[C4];
#pragma unroll
    for (int c = 0; c < C4; ++c)
        ev[c] = e64[((size_t)c * B_ + b) * S_ + s];   // independent, deep ILP
    float aw = a64[s];
    float Z = z0[b * S_ + s];
#pragma unroll
    for (int c = 0; c < C4; ++c) {
        cin[((size_t)c * B_ + b) * S_ + s] = Z;
        Z = fmaf(aw, Z, ev[c]);
    }
}

// ---------------- K4: per-chunk scan + out, x2 s-vectorized ----------------
// Block (c,g): wave w -> b = g*2 + (w>>1), s-half = (w&1); lane -> 2 s values.
__global__ __launch_bounds__(256) void k_scan(
        const __hip_bfloat16* __restrict__ ub, const float* __restrict__ cin,
        const float* __restrict__ abar, float* __restrict__ out) {
    const int c = blockIdx.x, g = blockIdx.y;
    const int w = threadIdx.x >> 6, lane = threadIdx.x & 63;
    const int b = g * 2 + (w >> 1);
    const int s0 = (w & 1) * 128 + lane * 2;
    float2 a = *(const float2*)(abar + s0);
    float2 z = *(const float2*)(cin + ((size_t)c * B_ + b) * S_ + s0);
    const char* up = (const char*)(ub + ((size_t)b * T_ + c * WND) * S_ + s0);
    float* op = out + ((size_t)(c * WND) * B_ + b) * S_ + s0;
#pragma unroll 8
    for (int t = 0; t < WND; ++t) {
        ushort2 v = *(const ushort2*)up;           // 4 B/lane, 256 B/wave
        z.x = fmaf(a.x, z.x, bfbits(v.x));
        z.y = fmaf(a.y, z.y, bfbits(v.y));
        *(float2*)op = z;                          // 8 B/lane, 512 B/wave
        up += S_ * 2;
        op += (size_t)B_ * S_;
    }
}

extern "C" void kernel_launch(void* const* d_in, const int* in_sizes, int n_in,
                              void* d_out, int out_size, void* d_ws, size_t ws_size,
                              hipStream_t stream) {
    const float* x   = (const float*)d_in[0];  // [T,B,D]
    const float* z0  = (const float*)d_in[1];  // [B,S]
    const float* lna = (const float*)d_in[2];  // [S]
    const float* bm  = (const float*)d_in[3];  // [S,D]
    const float* ldt = (const float*)d_in[4];  // [S]
    float* out = (float*)d_out;

    char* ws = (char*)d_ws;
    float*          abar = (float*)ws;                              // 1 KiB
    float*          a64  = (float*)(ws + 4096);                     // 1 KiB
    __hip_bfloat16* bbar = (__hip_bfloat16*)(ws + 8192);            // 64 KiB
    float*          e64  = (float*)(ws + (128 << 10));              // 1 MiB
    float*          cin  = (float*)(ws + (128 << 10) + (1 << 20));  // 1 MiB
    __hip_bfloat16* ub   = (__hip_bfloat16*)(ws + (4 << 20));       // 32 MiB [b][t][s]

    k_params<<<129, 256, 0, stream>>>(lna, bm, ldt, abar, a64, bbar);
    k_gemm<<<dim3(C4, B_), 256, 0, stream>>>(x, bbar, abar, ub, e64);
    k_carry<<<B_, 256, 0, stream>>>(e64, a64, z0, cin);
    k_scan<<<dim3(C4, B_/2), 256, 0, stream>>>(ub, cin, abar, out);
}